// Round 1
// baseline (140.896 us; speedup 1.0000x reference)
//
#include <hip/hip_runtime.h>
#include <stdint.h>

#define N_BOXES 6000
#define NT 94            // real tiles of 64
#define NTP 96           // padded tile count (unroll-3 pipeline)
#define NROWS (NTP * 64) // 6144 padded rows
#define CAP 16           // u16 suppression-list entries per row (sentinel 0xFFFF)
#define IOU_THR 0.5f
#define CONF_THR 0.6f

typedef unsigned long long u64;
typedef unsigned int u32;
typedef unsigned short u16;

__device__ __forceinline__ u64 rdlane64(u64 v, int l) {
    unsigned lo = (unsigned)__builtin_amdgcn_readlane((int)(unsigned)v, l);
    unsigned hi = (unsigned)__builtin_amdgcn_readlane((int)(unsigned)(v >> 32), l);
    return ((u64)hi << 32) | lo;
}

// ---- kernel 1: fused sort (keys + rank + scatter) + workspace init --------
// scores uniform [0,1) -> raw float bits monotone. key = (~bits<<32)|index:
// ascending u64 == descending score, ties by ascending index (JAX stable argsort).
// LDS-staged keys, broadcast ds_read compares (scalar-pipe attempt in R8
// regressed: compiler emits serialized global loads, not s_load).
__global__ void __launch_bounds__(1024) k_sort(const float* __restrict__ scores,
                                               const float4* __restrict__ boxes,
                                               int* __restrict__ sidx,
                                               float4* __restrict__ sboxes,
                                               u32* __restrict__ lists_w,  // lists as u32
                                               int* __restrict__ cnt) {
    __shared__ u64 kt[N_BOXES];      // 48,000 B
    __shared__ int part[1024];
    const int tid = threadIdx.x;
    const int gtid = blockIdx.x * 1024 + tid;
    // init sparse-list sentinels + slot counters (spread over 96k threads)
    for (int j = gtid; j < NROWS * CAP / 2; j += NT * 1024) lists_w[j] = 0xFFFFFFFFu;
    for (int j = gtid; j < NROWS; j += NT * 1024) cnt[j] = 0;

    for (int j = tid; j < N_BOXES; j += 1024) {
        unsigned inv = ~__float_as_uint(scores[j]);
        kt[j] = ((u64)inv << 32) | (unsigned)j;
    }
    __syncthreads();
    const int il = tid & 63;
    const int i = blockIdx.x * 64 + il;
    const int j0 = (tid >> 6) * 375;         // 16 segments of 375 (wave-uniform)
    u64 mykey = (i < N_BOXES) ? kt[i] : 0ull;
    int cntr = 0;
#pragma unroll 5
    for (int jj = 0; jj < 375; ++jj)
        cntr += (kt[j0 + jj] < mykey) ? 1 : 0;
    part[tid] = cntr;
    __syncthreads();
    if (tid < 64 && i < N_BOXES) {
        int r = 0;
#pragma unroll
        for (int s = 0; s < 16; ++s) r += part[il + 64 * s];
        sidx[r] = i;                 // keys distinct -> permutation
        sboxes[r] = boxes[i];
    }
}

// ---- kernel 2: pairwise IoU -> SPARSE suppression lists + diag words ------
// In-tile (diagonal-block) edges go ONLY to diagw — k_scan's resolve handles
// them — so scatter in k_scan never touches removed[T] during tile T.
__global__ void k_mask(const float4* __restrict__ sboxes,
                       u16* __restrict__ lists, int* __restrict__ cnt,
                       u64* __restrict__ diagw) {
    int ct = blockIdx.x, rt = blockIdx.y;
    if (ct < rt) return;
    int lane = threadIdx.x;
    __shared__ float4 rb[64];
    int row0 = rt * 64;
    int rows = min(64, N_BOXES - row0);
    if (lane < rows) rb[lane] = sboxes[row0 + lane];
    __syncthreads();
    int j = ct * 64 + lane;
    bool jvalid = (j < N_BOXES);
    float4 cb = make_float4(0.f, 0.f, 1.f, 1.f);
    if (jvalid) cb = sboxes[j];
    float carea = (cb.z - cb.x) * (cb.w - cb.y);
    bool isdiag = (ct == rt);
    for (int i = 0; i < rows; ++i) {
        float4 rbx = rb[i];
        float rarea = (rbx.z - rbx.x) * (rbx.w - rbx.y);
        // identical f32 op order as the reference (_pairwise_iou)
        float iw = fmaxf(fminf(rbx.z, cb.z) - fmaxf(rbx.x, cb.x), 0.f);
        float ih = fmaxf(fminf(rbx.w, cb.w) - fmaxf(rbx.y, cb.y), 0.f);
        float inter = iw * ih;
        float iou = inter / ((rarea + carea) - inter);
        int row = row0 + i;
        bool pred = jvalid && (j > row) && (iou > IOU_THR);
        if (isdiag) {
            u64 bal = __ballot(pred);
            if (lane == (i & 63)) diagw[row] = bal;
        } else if (pred) {           // cross-tile edges only (~rare)
            int slot = atomicAdd(&cnt[row], 1);
            if (slot < CAP) lists[row * CAP + slot] = (u16)j;
        }
    }
}

// ---- kernel 3: greedy scan — SINGLE WAVE, zero barriers -------------------
// Wave 0 (64 lanes, lane = local row) runs the whole 96-tile scan with NO
// s_barrier: the LDS DS pipe is in-order per wave, so the ds_read of
// removed[T+1] issued right after tile T's scatter atomicOrs is guaranteed to
// see them, and its ~120-cyc latency hides under kw-write + prefetch issue +
// next tile's nz/valid math. All scatter targets are strictly-future tiles
// (lists hold only cross-tile j>row edges), so removed[T] is final once the
// scatters of tiles <T have issued — which, single-wave, is program order.
// Waves 1-3 stream-touch lists+diagw (written by k_mask on all 8 XCDs) to
// pull them into THIS XCD's L2, then park in one __syncthreads until the
// 256-thread epilogue. Distance-3 rotating register prefetch as before.
__global__ void __launch_bounds__(256) k_scan(const u16* __restrict__ lists,
                                              const u64* __restrict__ diagw,
                                              const int* __restrict__ sidx,
                                              const float* __restrict__ scores,
                                              float* __restrict__ out) {
    __shared__ u64 removed[NTP];
    __shared__ u64 kwbuf[NTP];
    const int tid = threadIdx.x;
    if (tid < NTP) removed[tid] = 0;
    __syncthreads();   // removed[] visible to wave 0 before the scan

    if (tid >= 64) {
        // ---- L2 warm: pull k_mask's output into the local XCD's L2 ----
        const uint4* lv = (const uint4*)lists;   // 196,608 B = 12,288 uint4
        const uint4* dv = (const uint4*)diagw;   //  49,152 B =  3,072 uint4
        u32 acc = 0;
        for (int j = tid - 64; j < 12288; j += 192) {
            uint4 v = lv[j];
            acc ^= v.x ^ v.y ^ v.z ^ v.w;
        }
        for (int j = tid - 64; j < 3072; j += 192) {
            uint4 v = dv[j];
            acc ^= v.x ^ v.y ^ v.z ^ v.w;
        }
        asm volatile("" :: "v"(acc));   // keep the warming loads live (rule #17)
    } else {
        const int lane = tid;
        // distance-3 rotating prefetch: full 16-entry row list (32 B) + diag
        uint4 A0 = *(const uint4*)&lists[(0 * 64 + lane) * CAP];
        uint4 B0 = *(const uint4*)&lists[(0 * 64 + lane) * CAP + 8];
        uint4 A1 = *(const uint4*)&lists[(1 * 64 + lane) * CAP];
        uint4 B1 = *(const uint4*)&lists[(1 * 64 + lane) * CAP + 8];
        uint4 A2 = *(const uint4*)&lists[(2 * 64 + lane) * CAP];
        uint4 B2 = *(const uint4*)&lists[(2 * 64 + lane) * CAP + 8];
        u64 D0 = diagw[0 * 64 + lane];
        u64 D1 = diagw[1 * 64 + lane];
        u64 D2 = diagw[2 * 64 + lane];
        u64 rmn = 0;   // removed[0] provably 0: no scatters yet

// scatter one u32 (2 entries); fill order => e0 valid whenever w != sentinel
#define SC2(w)                                                                 \
        if ((w) != 0xFFFFFFFFu) {                                              \
            u16 e0 = (u16)(w), e1 = (u16)((w) >> 16);                          \
            atomicOr(&removed[e0 >> 6], 1ull << (e0 & 63));                    \
            if (e1 != 0xFFFFu) atomicOr(&removed[e1 >> 6], 1ull << (e1 & 63)); \
        }

#define STEP(T, A, B, DD)                                                      \
        {                                                                      \
            const u64 nz = __ballot(DD != 0ull);  /* in-tile suppressors */    \
            const int row0 = (T) * 64;                                         \
            const int rem = N_BOXES - row0;                                    \
            const u64 valid = (rem >= 64) ? ~0ull                              \
                            : ((rem <= 0) ? 0ull : ((1ull << rem) - 1ull));    \
            u64 c = valid & ~rmn;                                              \
            u64 kw = 0;                                                        \
            while (c) {                                                        \
                u64 blockers = c & nz;                                         \
                if (!blockers) { kw |= c; break; }   /* bulk-keep rest */      \
                int g = (int)__builtin_ctzll(blockers);                        \
                u64 below = c & ((1ull << g) - 1ull); /* zero-diag: kept */    \
                kw |= below | (1ull << g);                                     \
                u64 df = rdlane64(DD, g);             /* bits > g only */      \
                c &= ~(df | below | (1ull << g));                              \
            }                                                                  \
            if (((kw >> lane) & 1ull) && A.x != 0xFFFFFFFFu) {                 \
                SC2(A.x) SC2(A.y) SC2(A.z) SC2(A.w)                            \
                SC2(B.x) SC2(B.y) SC2(B.z) SC2(B.w)                            \
            }                                                                  \
            /* issue next removed read AFTER this tile's atomics (in-order */  \
            /* DS pipe => sees every scatter from tiles <= T)             */   \
            rmn = removed[((T) + 1 < NTP) ? (T) + 1 : 0];                      \
            if (lane == 0) kwbuf[(T)] = kw;                                    \
            const int tn = ((T) + 3 < NTP) ? ((T) + 3) : ((T) + 3 - NTP);      \
            A = *(const uint4*)&lists[(tn * 64 + lane) * CAP];                 \
            B = *(const uint4*)&lists[(tn * 64 + lane) * CAP + 8];             \
            DD = diagw[tn * 64 + lane];                                        \
        }

        for (int t = 0; t < NTP; t += 3) {   // NTP = 96 = 32 x 3
            STEP(t,     A0, B0, D0)
            STEP(t + 1, A1, B1, D1)
            STEP(t + 2, A2, B2, D2)
        }
#undef STEP
#undef SC2
    }
    __syncthreads();   // kwbuf complete; warming waves rejoin

    // ---- epilogue: masked scores through the sort permutation ----
    for (int p = tid; p < N_BOXES; p += 256) {
        int orig = sidx[p];
        float s = scores[orig];
        bool k = (kwbuf[p >> 6] >> (p & 63)) & 1ull;
        out[orig] = (k && (s >= CONF_THR)) ? s : 0.0f;  // writes ALL outputs
    }
}

extern "C" void kernel_launch(void* const* d_in, const int* in_sizes, int n_in,
                              void* d_out, int out_size, void* d_ws, size_t ws_size,
                              hipStream_t stream) {
    const float* boxes  = (const float*)d_in[0];    // [6000,4]
    const float* scores = (const float*)d_in[1];    // [6000]
    float* out = (float*)d_out;                     // [6000]

    // workspace layout
    char* ws = (char*)d_ws;
    u16*    lists  = (u16*)(ws);                    // 6144*16*2 = 196,608 B
    int*    cnt    = (int*)(ws + 196608);           // 6144*4    =  24,576 B
    u64*    diagw  = (u64*)(ws + 221184);           // 96*64*8   =  49,152 B
    int*    sidx   = (int*)(ws + 270336);           // 24,000 B
    float4* sboxes = (float4*)(ws + 294336);        // 96,000 B (16B aligned)

    k_sort<<<dim3(NT), dim3(1024), 0, stream>>>(scores, (const float4*)boxes, sidx,
                                                sboxes, (u32*)lists, cnt);
    k_mask<<<dim3(NT, NT), dim3(64), 0, stream>>>((const float4*)sboxes, lists, cnt, diagw);
    k_scan<<<dim3(1), dim3(256), 0, stream>>>(lists, diagw, sidx, scores, out);
}